// Round 2
// baseline (3595.275 us; speedup 1.0000x reference)
//
#include <hip/hip_runtime.h>

// Output layout (flat): x_residual[2048*62*64], Sloss, dloss, S[2048*62*62]
#define XR_OFF 0
#define SL_OFF 8126464
#define DL_OFF 8126465
#define S_OFF  8126466

#define ALPHA_F 1e-4f
#define INV_SQRT310 0.05679618342470648f  // 1/sqrt(62*5)
#define INV_SQRT15  0.2581988897471611f   // 1/sqrt(3*5)

// ws layout (float offsets)
#define WS_TWT  0              // 12288 floats  (tw transposed [t][c][o])
#define WS_DIAG 12288          // 2048*62 = 126976
#define WS_C1   139264         // 2048*3844 = 7872512
#define WS_C2   8011776        // 7872512     (end: 15884288 floats = 63.5 MB)

// Prep: transpose tw (o,c,t) -> twt (t,c,o); zero the two loss accumulators.
__global__ void prep_kernel(const float* __restrict__ tw, float* __restrict__ ws,
                            float* __restrict__ out) {
    int i = blockIdx.x * 256 + threadIdx.x;
    if (i < 12288) {
        int t = i >> 12, r = i & 4095, c = r >> 6, o = r & 63;
        ws[WS_TWT + i] = tw[o * 192 + c * 3 + t];
    }
    if (i < 2) out[SL_OFF + i] = 0.f;
}

// ---------------- Kernel A: attention + S + losses + C1/C2/diag ----------------
__launch_bounds__(256, 4)
__global__ void attn_kernel(
    const float* __restrict__ x,  const float* __restrict__ U1,
    const float* __restrict__ U2, const float* __restrict__ U3,
    const float* __restrict__ be, const float* __restrict__ Ve,
    const float* __restrict__ W1, const float* __restrict__ W2,
    const float* __restrict__ W3, const float* __restrict__ bs,
    const float* __restrict__ Vs, const float* __restrict__ a,
    float* __restrict__ ws, float* __restrict__ out)
{
    __shared__ float sx[930];                      // x[b] [t][v][f]
    __shared__ float sxT[930];                     // x_TAt [u][v][f]
    __shared__ __align__(16) float buf1[3968];     // z2 / sigmoid[62][64] / tmpS[62][62]
    __shared__ float buf2[3844];                   // Sm -> spatial_At  [u][v] stride 62
    __shared__ float sL[186], sR[186];
    __shared__ float sy[15], sprod[9], sE[9], stAt[9];
    __shared__ float scol[62], sred[16];

    const int b   = blockIdx.x;
    const int tid = threadIdx.x;
    const int q   = tid >> 6;

    for (int i = tid; i < 930; i += 256) sx[i] = x[(size_t)b * 930 + i];
    __syncthreads();

    // ---- temporal attention ----
    if (tid < 15) {
        int t = tid / 5, f = tid % 5;
        float s = 0.f;
        for (int v = 0; v < 62; ++v) s += sx[t * 310 + v * 5 + f] * U1[v];
        sy[tid] = s;
    }
    if (tid < 186) {
        int v = tid / 3, t = tid % 3;
        float s = 0.f;
        for (int f = 0; f < 5; ++f) s += U3[f] * sx[t * 310 + v * 5 + f];
        sR[v * 3 + t] = s;
    }
    __syncthreads();
    if (tid < 186) {
        int t = tid / 62, u = tid % 62;
        float s = 0.f;
        for (int f = 0; f < 5; ++f) s += sy[t * 5 + f] * U2[f * 62 + u];
        sL[t * 62 + u] = s;
    }
    __syncthreads();
    if (tid < 9) {
        int t = tid / 3, u = tid % 3;
        float s = 0.f;
        for (int v = 0; v < 62; ++v) s += sL[t * 62 + v] * sR[v * 3 + u];
        sprod[tid] = s;
    }
    __syncthreads();
    if (tid < 9) {
        int t = tid / 3, u = tid % 3;
        float s = 0.f;
        for (int ss = 0; ss < 3; ++ss) {
            float p  = sprod[ss * 3 + u] + be[ss * 3 + u];
            s += Ve[t * 3 + ss] * (1.f / (1.f + __expf(-p)));
        }
        sE[tid] = s;
    }
    __syncthreads();
    if (tid < 3) {
        int u = tid;
        float m = fmaxf(sE[u], fmaxf(sE[3 + u], sE[6 + u]));
        float e0 = __expf(sE[u] - m), e1 = __expf(sE[3 + u] - m), e2 = __expf(sE[6 + u] - m);
        float inv = 1.f / (e0 + e1 + e2);
        stAt[u] = e0 * inv; stAt[3 + u] = e1 * inv; stAt[6 + u] = e2 * inv;
    }
    __syncthreads();
    for (int i = tid; i < 930; i += 256) {
        int u = i / 310, r = i % 310;
        float s = 0.f;
        for (int t = 0; t < 3; ++t) s += sx[t * 310 + r] * stAt[t * 3 + u];
        sxT[i] = s * INV_SQRT310;
    }
    __syncthreads();

    // ---- spatial attention ----
    for (int i = tid; i < 310; i += 256) {          // z2 -> buf1[0..310)
        float s = 0.f;
        for (int t = 0; t < 3; ++t) s += sxT[t * 310 + i] * W1[t];
        buf1[i] = s;
    }
    if (tid < 186) {                                 // s_rhs[t][v]
        int t = tid / 62, v = tid % 62;
        float s = 0.f;
        for (int f = 0; f < 5; ++f) s += W3[f] * sxT[t * 310 + v * 5 + f];
        sR[t * 62 + v] = s;
    }
    __syncthreads();
    if (tid < 186) {                                 // s_lhs[v][t]
        int v = tid / 3, s3 = tid % 3;
        float s = 0.f;
        for (int f = 0; f < 5; ++f) s += buf1[v * 5 + f] * W2[f * 3 + s3];
        sL[v * 3 + s3] = s;
    }
    __syncthreads();
    // sigmoid matrix, padded stride 64 (cols 62,63 zeroed)
    for (int i = tid; i < 3968; i += 256) {
        int u = i >> 6, v = i & 63;
        float val = 0.f;
        if (v < 62) {
            float s = bs[u * 62 + v];
            for (int t = 0; t < 3; ++t) s += sL[u * 3 + t] * sR[t * 62 + v];
            val = 1.f / (1.f + __expf(-s));
        }
        buf1[i] = val;
    }
    __syncthreads();
    // Sm = Vs @ sig : u-paired, float4 over v
    for (int g = tid; g < 496; g += 256) {
        int up = g >> 4, vg = (g & 15) << 2;
        int u1 = up, u2 = up + 31;
        const float* vr1 = Vs + u1 * 62;
        const float* vr2 = Vs + u2 * 62;
        float a1x=0.f,a1y=0.f,a1z=0.f,a1w=0.f, a2x=0.f,a2y=0.f,a2z=0.f,a2w=0.f;
        for (int w = 0; w < 62; ++w) {
            float4 s4 = *(const float4*)&buf1[(w << 6) + vg];
            float p1 = vr1[w], p2 = vr2[w];
            a1x += p1 * s4.x; a1y += p1 * s4.y; a1z += p1 * s4.z; a1w += p1 * s4.w;
            a2x += p2 * s4.x; a2y += p2 * s4.y; a2z += p2 * s4.z; a2w += p2 * s4.w;
        }
        buf2[u1 * 62 + vg]     = a1x;
        buf2[u1 * 62 + vg + 1] = a1y;
        buf2[u2 * 62 + vg]     = a2x;
        buf2[u2 * 62 + vg + 1] = a2y;
        if (vg < 60) {
            buf2[u1 * 62 + vg + 2] = a1z; buf2[u1 * 62 + vg + 3] = a1w;
            buf2[u2 * 62 + vg + 2] = a2z; buf2[u2 * 62 + vg + 3] = a2w;
        }
    }
    __syncthreads();
    // spatial softmax over u (columns of buf2)
    if (tid < 62) {
        int v = tid;
        float m = -1e30f;
        for (int u = 0; u < 62; ++u) m = fmaxf(m, buf2[u * 62 + v]);
        float den = 0.f;
        for (int u = 0; u < 62; ++u) {
            float e = __expf(buf2[u * 62 + v] - m);
            buf2[u * 62 + v] = e;
            den += e;
        }
        float inv = 1.f / den;
        for (int u = 0; u < 62; ++u) buf2[u * 62 + v] *= inv;
    }
    // tmpS into buf1 (stride 62), concurrent with softmax (disjoint buffers)
    for (int idx = tid; idx < 3844; idx += 256) {
        int i = idx / 62, j = idx - i * 62;
        float s = 0.f;
        #pragma unroll
        for (int f = 0; f < 5; ++f)
            s += fabsf(sx[310 + i * 5 + f] - sx[310 + j * 5 + f]) * a[f];
        buf1[idx] = __expf(fmaxf(s, 0.f));
    }
    __syncthreads();
    if (tid < 62) {
        int j = tid;
        float s = 0.f;
        for (int i = 0; i < 62; ++i) s += buf1[i * 62 + j];
        scol[j] = 1.f / s;
    }
    if (tid < 5) {   // dloss closed form: sum d2 = sum_f (2*62*sum xm^2 - 2*(sum xm)^2)
        float su = 0.f, sq = 0.f;
        for (int v = 0; v < 62; ++v) {
            float xv = sx[310 + v * 5 + tid];
            su += xv; sq += xv * xv;
        }
        sred[8 + tid] = 124.f * sq - 2.f * su * su;
    }
    __syncthreads();
    // S out, Sloss, C1/C2/diag writes
    float slp = 0.f;
    const size_t bo = (size_t)b * 3844;
    for (int idx = tid; idx < 3844; idx += 256) {
        int i = idx / 62, j = idx - i * 62;
        float sv = buf1[idx] * scol[j];
        out[S_OFF + bo + idx] = sv;
        slp += sv * sv;
        float A = buf2[idx];
        if (i == j) ws[WS_DIAG + b * 62 + i] = A;
        ws[WS_C1 + bo + idx] = sv * A;
        float c2 = 2.f * sv * sv - ((i == j) ? 1.f : 0.f);
        ws[WS_C2 + bo + idx] = c2 * A;
    }
    #pragma unroll
    for (int m = 32; m > 0; m >>= 1) slp += __shfl_down(slp, m, 64);
    if ((tid & 63) == 0) sred[q] = slp;
    __syncthreads();
    if (tid == 0) {
        atomicAdd(out + SL_OFF, (sred[0] + sred[1] + sred[2] + sred[3]) * (ALPHA_F / 2048.f));
        atomicAdd(out + DL_OFF, (sred[8] + sred[9] + sred[10] + sred[11] + sred[12]) * ALPHA_F);
    }
}

// ---------------- Kernel B: GCN + temporal conv + residual + LayerNorm ----------------
__launch_bounds__(256, 4)
__global__ void gcn_kernel(
    const float* __restrict__ x,  const float* __restrict__ Theta,
    const float* __restrict__ rw, const float* __restrict__ rb,
    const float* __restrict__ tb, const float* __restrict__ gamma_,
    const float* __restrict__ beta_, const float* __restrict__ ws,
    float* __restrict__ out)
{
    __shared__ float sx[930];                 // x[b]
    __shared__ float sTh[960];                // Theta [kf15][o64]
    __shared__ float sG[1920];                // G [t][kf10][v64pad]  (k=1,2 parts)
    __shared__ float sdiag[62];
    __shared__ __align__(16) float gbuf[4][64];

    const int b   = blockIdx.x;
    const int tid = threadIdx.x;
    const int o   = tid & 63;
    const int q   = tid >> 6;
    const float* twt = ws + WS_TWT;
    const float* C1g = ws + WS_C1 + (size_t)b * 3844;
    const float* C2g = ws + WS_C2 + (size_t)b * 3844;

    for (int i = tid; i < 930; i += 256) sx[i] = x[(size_t)b * 930 + i];
    for (int i = tid; i < 960; i += 256) sTh[i] = Theta[i];
    if (tid < 62) sdiag[tid] = ws[WS_DIAG + b * 62 + tid];
    __syncthreads();

    // step1: G[t][kf][v] for k=1 (-C1^T x) and k=2 (+C2^T x); lane=v, wave=round-slot
    {
        const int v = o;
        float g1a[4] = {0.f,0.f,0.f,0.f}, g2a[4] = {0.f,0.f,0.f,0.f};
        if (v < 62) {
            #pragma unroll
            for (int ub = 0; ub < 4; ++ub) {
                const int u0 = ub * 16;
                const int un = (ub == 3) ? 14 : 16;
                float c1r[16], c2r[16];
                #pragma unroll
                for (int k = 0; k < 16; ++k) {
                    if (k < un) {
                        c1r[k] = C1g[(u0 + k) * 62 + v];   // coalesced over v
                        c2r[k] = C2g[(u0 + k) * 62 + v];
                    }
                }
                #pragma unroll
                for (int ri = 0; ri < 4; ++ri) {
                    int r = q + 4 * ri;
                    if (r < 15) {
                        int t = (r >= 10) ? 2 : ((r >= 5) ? 1 : 0);
                        int f = r - t * 5;
                        float a1 = g1a[ri], a2 = g2a[ri];
                        #pragma unroll
                        for (int k = 0; k < 16; ++k) {
                            if (k < un) {
                                float xa = sx[t * 310 + (u0 + k) * 5 + f];  // broadcast
                                a1 -= c1r[k] * xa;
                                a2 += c2r[k] * xa;
                            }
                        }
                        g1a[ri] = a1; g2a[ri] = a2;
                    }
                }
            }
            #pragma unroll
            for (int ri = 0; ri < 4; ++ri) {
                int r = q + 4 * ri;
                if (r < 15) {
                    int t = (r >= 10) ? 2 : ((r >= 5) ? 1 : 0);
                    int f = r - t * 5;
                    sG[t * 640 + f * 64 + v]       = g1a[ri];
                    sG[t * 640 + (5 + f) * 64 + v] = g2a[ri];
                }
            }
        }
    }
    __syncthreads();

    // step2/3: barrier-free per wave. lane=o, wave q owns v = q+4j.
    const int nv = (q < 2) ? 16 : 15;
    float rw5[5];
    #pragma unroll
    for (int f = 0; f < 5; ++f) rw5[f] = rw[o * 5 + f];
    const float rb_o = rb[o], tb_o = tb[o], gam = gamma_[o], bet = beta_[o];

    float acc[16];
    #pragma unroll
    for (int j = 0; j < 16; ++j) acc[j] = 0.f;

    for (int t = 0; t < 3; ++t) {
        float twreg[64];
        #pragma unroll
        for (int c = 0; c < 64; ++c) twreg[c] = twt[t * 4096 + c * 64 + o];  // coalesced, L1-hot
        const float* sxt = sx + t * 310;
        const float* sGt = sG + t * 640;
        #pragma unroll
        for (int j = 0; j < 16; ++j) {
            if (j < nv) {
                const int v = q + 4 * j;
                float dv = sdiag[v];
                float ssum = 0.f;
                #pragma unroll
                for (int f = 0; f < 5; ++f) ssum += (dv * sxt[v * 5 + f]) * sTh[f * 64 + o];
                #pragma unroll
                for (int kf = 0; kf < 10; ++kf) ssum += sGt[kf * 64 + v] * sTh[(kf + 5) * 64 + o];
                gbuf[q][o] = fmaxf(ssum, 0.f);       // wave-private; in-order LDS pipe
                const float4* gb4 = (const float4*)gbuf[q];
                float aj = acc[j];
                #pragma unroll
                for (int c4 = 0; c4 < 16; ++c4) {
                    float4 g4 = gb4[c4];
                    aj += g4.x * twreg[4 * c4 + 0];
                    aj += g4.y * twreg[4 * c4 + 1];
                    aj += g4.z * twreg[4 * c4 + 2];
                    aj += g4.w * twreg[4 * c4 + 3];
                }
                acc[j] = aj;
            }
        }
    }

    // epilogue: residual + relu + LayerNorm over o (wave shuffles)
    #pragma unroll
    for (int j = 0; j < 16; ++j) {
        if (j < nv) {
            int v = q + 4 * j;
            float r = rb_o;
            #pragma unroll
            for (int f = 0; f < 5; ++f) r += sx[v * 5 + f] * rw5[f];   // x[:,0]
            float z = r + (acc[j] + tb_o) * INV_SQRT15;
            z = fmaxf(z, 0.f);
            float s1 = z, s2 = z * z;
            #pragma unroll
            for (int m = 1; m < 64; m <<= 1) {
                s1 += __shfl_xor(s1, m, 64);
                s2 += __shfl_xor(s2, m, 64);
            }
            float mean = s1 * 0.015625f;
            float var  = s2 * 0.015625f - mean * mean;
            out[XR_OFF + (size_t)b * 3968 + v * 64 + o] =
                (z - mean) * rsqrtf(var + 1e-5f) * gam + bet;
        }
    }
}

extern "C" void kernel_launch(void* const* d_in, const int* in_sizes, int n_in,
                              void* d_out, int out_size, void* d_ws, size_t ws_size,
                              hipStream_t stream) {
    const float* x   = (const float*)d_in[0];
    const float* U1  = (const float*)d_in[1];
    const float* U2  = (const float*)d_in[2];
    const float* U3  = (const float*)d_in[3];
    const float* be  = (const float*)d_in[4];
    const float* Ve  = (const float*)d_in[5];
    const float* W1  = (const float*)d_in[6];
    const float* W2  = (const float*)d_in[7];
    const float* W3  = (const float*)d_in[8];
    const float* bs  = (const float*)d_in[9];
    const float* Vs  = (const float*)d_in[10];
    const float* a   = (const float*)d_in[11];
    const float* Th  = (const float*)d_in[12];
    const float* tw  = (const float*)d_in[13];
    const float* tb  = (const float*)d_in[14];
    const float* rw  = (const float*)d_in[15];
    const float* rb  = (const float*)d_in[16];
    const float* gm  = (const float*)d_in[17];
    const float* bt  = (const float*)d_in[18];
    float* out = (float*)d_out;
    float* ws  = (float*)d_ws;   // needs ~63.6 MB

    prep_kernel<<<48, 256, 0, stream>>>(tw, ws, out);
    attn_kernel<<<2048, 256, 0, stream>>>(x, U1, U2, U3, be, Ve, W1, W2, W3,
                                          bs, Vs, a, ws, out);
    gcn_kernel<<<2048, 256, 0, stream>>>(x, Th, rw, rb, tb, gm, bt, ws, out);
}

// Round 3
// 645.864 us; speedup vs baseline: 5.5666x; 5.5666x over previous
//
#include <hip/hip_runtime.h>

// Output layout (flat): x_residual[2048*62*64], Sloss, dloss, S[2048*62*62]
#define XR_OFF 0
#define SL_OFF 8126464
#define DL_OFF 8126465
#define S_OFF  8126466

#define ALPHA_F 1e-4f
#define INV_SQRT310 0.05679618342470648f  // 1/sqrt(62*5)
#define INV_SQRT15  0.2581988897471611f   // 1/sqrt(3*5)

// Single LDS array, hand-packed (floats). Total 13410 floats = 53640 B -> 3 blocks/CU.
#define L_SX 0        // 932   x[b] [t][v][f] (930 used)
#define L_A  932      // 3844  tmpS -> S -> C1            [u][v] stride 62
#define L_B  4776     // 3844  Sm -> expAt -> C2          [u][v] stride 62
#define L_C  8620     // 3968  sxT(0:930)+z2(930:1240) -> sigmoid[62][64] -> softmax scratch -> gcn[62][64]
#define L_D  12588    // 822   smalls / G[62][12] / diag / sred
#define LDS_N 13410

// D-region offsets (stages B-D smalls; dead before stage F G writes)
#define D_SL   0      // 186
#define D_SR   186    // 186
#define D_SY   372    // 15
#define D_PROD 388    // 9
#define D_SE   400    // 9
#define D_TAT  412    // 9
#define D_SCOL 424    // 62  (read in transform, dead after)
// stage F / persistent
#define D_G    0      // 744 = [62][12]
#define D_DIAG 744    // 62
#define D_SRED 806    // 16

// Prep: transpose tw (o,c,t) -> twt (t,c,o); zero the two loss accumulators.
__global__ void prep_kernel(const float* __restrict__ tw, float* __restrict__ twt,
                            float* __restrict__ out) {
    int i = blockIdx.x * 256 + threadIdx.x;
    if (i < 12288) {
        int t = i >> 12, r = i & 4095, c = r >> 6, o = r & 63;
        twt[i] = tw[o * 192 + c * 3 + t];
    }
    if (i < 2) out[SL_OFF + i] = 0.f;
}

__launch_bounds__(256, 3)
__global__ void stgcn_kernel(
    const float* __restrict__ x,     const float* __restrict__ U1,
    const float* __restrict__ U2,    const float* __restrict__ U3,
    const float* __restrict__ be,    const float* __restrict__ Ve,
    const float* __restrict__ W1,    const float* __restrict__ W2,
    const float* __restrict__ W3,    const float* __restrict__ bs,
    const float* __restrict__ Vs,    const float* __restrict__ aF,
    const float* __restrict__ Theta, const float* __restrict__ twt,
    const float* __restrict__ tb,    const float* __restrict__ rw,
    const float* __restrict__ rb,    const float* __restrict__ gamma_,
    const float* __restrict__ beta_, float* __restrict__ out)
{
    __shared__ float lds[LDS_N];

    const int b   = blockIdx.x;
    const int tid = threadIdx.x;
    const int o   = tid & 63;
    const int q   = tid >> 6;
    const int nv  = (q < 2) ? 16 : 15;   // wave q owns v = q + 4j

    // persistent per-lane registers
    float th[15];
    #pragma unroll
    for (int kf = 0; kf < 15; ++kf) th[kf] = Theta[kf * 64 + o];
    float rw5[5];
    #pragma unroll
    for (int f = 0; f < 5; ++f) rw5[f] = rw[o * 5 + f];
    const float rb_o = rb[o], tb_o = tb[o], gam = gamma_[o], bet = beta_[o];

    // ---- load x[b] ----
    for (int i = tid; i < 930; i += 256) lds[L_SX + i] = x[(size_t)b * 930 + i];
    __syncthreads();

    // ---- temporal attention ----
    if (tid < 15) {                       // y[t][f] = sum_v x[t][v][f]*U1[v]
        int t = tid / 5, f = tid % 5;
        float s = 0.f;
        for (int v = 0; v < 62; ++v) s += lds[L_SX + t * 310 + v * 5 + f] * U1[v];
        lds[L_D + D_SY + tid] = s;
    }
    if (tid < 186) {                      // rhs[v][t] = sum_f U3[f]*x[t][v][f]
        int v = tid / 3, t = tid % 3;
        float s = 0.f;
        #pragma unroll
        for (int f = 0; f < 5; ++f) s += U3[f] * lds[L_SX + t * 310 + v * 5 + f];
        lds[L_D + D_SR + v * 3 + t] = s;
    }
    __syncthreads();
    if (tid < 186) {                      // lhs[t][u] = sum_f y[t][f]*U2[f][u]
        int t = tid / 62, u = tid % 62;
        float s = 0.f;
        #pragma unroll
        for (int f = 0; f < 5; ++f) s += lds[L_D + D_SY + t * 5 + f] * U2[f * 62 + u];
        lds[L_D + D_SL + t * 62 + u] = s;
    }
    __syncthreads();
    if (tid < 9) {                        // prod[t][u]
        int t = tid / 3, u = tid % 3;
        float s = 0.f;
        for (int v = 0; v < 62; ++v)
            s += lds[L_D + D_SL + t * 62 + v] * lds[L_D + D_SR + v * 3 + u];
        lds[L_D + D_PROD + tid] = s;
    }
    __syncthreads();
    if (tid < 9) {                        // E[t][u]
        int t = tid / 3, u = tid % 3;
        float s = 0.f;
        for (int ss = 0; ss < 3; ++ss) {
            float p = lds[L_D + D_PROD + ss * 3 + u] + be[ss * 3 + u];
            s += Ve[t * 3 + ss] * (1.f / (1.f + __expf(-p)));
        }
        lds[L_D + D_SE + tid] = s;
    }
    __syncthreads();
    if (tid < 3) {                        // softmax over t
        int u = tid;
        float e0v = lds[L_D + D_SE + u], e1v = lds[L_D + D_SE + 3 + u], e2v = lds[L_D + D_SE + 6 + u];
        float m = fmaxf(e0v, fmaxf(e1v, e2v));
        float e0 = __expf(e0v - m), e1 = __expf(e1v - m), e2 = __expf(e2v - m);
        float inv = 1.f / (e0 + e1 + e2);
        lds[L_D + D_TAT + u]     = e0 * inv;
        lds[L_D + D_TAT + 3 + u] = e1 * inv;
        lds[L_D + D_TAT + 6 + u] = e2 * inv;
    }
    __syncthreads();
    for (int i = tid; i < 930; i += 256) { // x_TAt -> C[0:930]
        int u = i / 310, r = i % 310;
        float s = 0.f;
        #pragma unroll
        for (int t = 0; t < 3; ++t) s += lds[L_SX + t * 310 + r] * lds[L_D + D_TAT + t * 3 + u];
        lds[L_C + i] = s * INV_SQRT310;
    }
    __syncthreads();

    // ---- spatial attention front-end ----
    for (int i = tid; i < 310; i += 256) { // z2 -> C[930:1240]
        float s = 0.f;
        #pragma unroll
        for (int t = 0; t < 3; ++t) s += lds[L_C + t * 310 + i] * W1[t];
        lds[L_C + 930 + i] = s;
    }
    if (tid < 186) {                       // s_rhs[t][v]
        int t = tid / 62, v = tid % 62;
        float s = 0.f;
        #pragma unroll
        for (int f = 0; f < 5; ++f) s += W3[f] * lds[L_C + t * 310 + v * 5 + f];
        lds[L_D + D_SR + t * 62 + v] = s;
    }
    __syncthreads();
    if (tid < 186) {                       // s_lhs[v][t]
        int v = tid / 3, s3 = tid % 3;
        float s = 0.f;
        #pragma unroll
        for (int f = 0; f < 5; ++f) s += lds[L_C + 930 + v * 5 + f] * W2[f * 3 + s3];
        lds[L_D + D_SL + v * 3 + s3] = s;
    }
    __syncthreads();
    // sigmoid matrix [62][64] (cols 62,63 = 0) -> C
    for (int i = tid; i < 3968; i += 256) {
        int u = i >> 6, v = i & 63;
        float val = 0.f;
        if (v < 62) {
            float s = bs[u * 62 + v];
            #pragma unroll
            for (int t = 0; t < 3; ++t)
                s += lds[L_D + D_SL + u * 3 + t] * lds[L_D + D_SR + t * 62 + v];
            val = 1.f / (1.f + __expf(-s));
        }
        lds[L_C + i] = val;
    }
    __syncthreads();
    // Sm = Vs @ sig -> B  (float4 over v), and tmpS -> A (same phase, disjoint)
    for (int it = tid; it < 992; it += 256) {
        int u = it >> 4, v4 = (it & 15) << 2;
        const float* vr = Vs + u * 62;
        float sx_ = 0.f, sy_ = 0.f, sz_ = 0.f, sw_ = 0.f;
        for (int w = 0; w < 62; ++w) {
            float4 g4 = *(const float4*)&lds[L_C + (w << 6) + v4];
            float p = vr[w];
            sx_ += p * g4.x; sy_ += p * g4.y; sz_ += p * g4.z; sw_ += p * g4.w;
        }
        lds[L_B + u * 62 + v4]     = sx_;
        lds[L_B + u * 62 + v4 + 1] = sy_;
        if (v4 < 60) {
            lds[L_B + u * 62 + v4 + 2] = sz_;
            lds[L_B + u * 62 + v4 + 3] = sw_;
        }
    }
    for (int idx = tid; idx < 3844; idx += 256) {
        int i2 = idx / 62, j = idx - i2 * 62;
        float s = 0.f;
        #pragma unroll
        for (int f = 0; f < 5; ++f)
            s += fabsf(lds[L_SX + 310 + i2 * 5 + f] - lds[L_SX + 310 + j * 5 + f]) * aF[f];
        lds[L_A + idx] = __expf(fmaxf(s, 0.f));
    }
    __syncthreads();

    // ---- parallel column reductions (softmax on B, colsum on A) ----
    {
        int seg = tid / 62, v = tid - seg * 62;
        int u0 = seg * 16, un = (seg == 3) ? 14 : 16;
        if (tid < 248) {   // Pa: partial max(B) and partial sum(A)
            float m = -1e30f, s = 0.f;
            for (int u = u0; u < u0 + un; ++u) {
                m = fmaxf(m, lds[L_B + u * 62 + v]);
                s += lds[L_A + u * 62 + v];
            }
            lds[L_C + tid]       = m;
            lds[L_C + 248 + tid] = s;
        }
        __syncthreads();
        if (tid < 62) {    // Pb: combine
            float m = fmaxf(fmaxf(lds[L_C + tid], lds[L_C + 62 + tid]),
                            fmaxf(lds[L_C + 124 + tid], lds[L_C + 186 + tid]));
            lds[L_C + 496 + tid] = m;
            float s = lds[L_C + 248 + tid] + lds[L_C + 310 + tid] +
                      lds[L_C + 372 + tid] + lds[L_C + 434 + tid];
            lds[L_D + D_SCOL + tid] = 1.f / s;
        } else if (tid >= 64 && tid < 69) {  // dloss partials (wave 1)
            int f = tid - 64;
            float su = 0.f, sq = 0.f;
            for (int v2 = 0; v2 < 62; ++v2) {
                float xv = lds[L_SX + 310 + v2 * 5 + f];
                su += xv; sq += xv * xv;
            }
            lds[L_D + D_SRED + 8 + f] = 124.f * sq - 2.f * su * su;
        }
        __syncthreads();
        if (tid < 248) {   // Pc: exp + partial sums
            float m = lds[L_C + 496 + v];
            float s = 0.f;
            for (int u = u0; u < u0 + un; ++u) {
                float e = __expf(lds[L_B + u * 62 + v] - m);
                lds[L_B + u * 62 + v] = e;
                s += e;
            }
            lds[L_C + tid] = s;
        }
        __syncthreads();
        if (tid < 62) {    // Pd: colinv
            float s = lds[L_C + tid] + lds[L_C + 62 + tid] +
                      lds[L_C + 124 + tid] + lds[L_C + 186 + tid];
            lds[L_C + 558 + tid] = 1.f / s;
        }
        __syncthreads();
    }

    // ---- transform: S out, Sloss, A<-C1, B<-C2, diag(At) ----
    float slp = 0.f;
    const size_t bo = (size_t)b * 3844;
    for (int idx = tid; idx < 3844; idx += 256) {
        int i2 = idx / 62, j = idx - i2 * 62;
        float sv = lds[L_A + idx] * lds[L_D + D_SCOL + j];
        out[S_OFF + bo + idx] = sv;
        slp += sv * sv;
        float At = lds[L_B + idx] * lds[L_C + 558 + j];
        if (i2 == j) lds[L_D + D_DIAG + i2] = At;
        lds[L_A + idx] = sv * At;                                   // C1
        lds[L_B + idx] = (2.f * sv * sv - ((i2 == j) ? 1.f : 0.f)) * At;  // C2
    }
    #pragma unroll
    for (int m = 32; m > 0; m >>= 1) slp += __shfl_down(slp, m, 64);
    if (o == 0) lds[L_D + D_SRED + q] = slp;
    __syncthreads();
    if (tid == 0) {
        atomicAdd(out + SL_OFF, (lds[L_D + D_SRED] + lds[L_D + D_SRED + 1] +
                                 lds[L_D + D_SRED + 2] + lds[L_D + D_SRED + 3]) * (ALPHA_F / 2048.f));
        atomicAdd(out + DL_OFF, (lds[L_D + D_SRED + 8] + lds[L_D + D_SRED + 9] +
                                 lds[L_D + D_SRED + 10] + lds[L_D + D_SRED + 11] +
                                 lds[L_D + D_SRED + 12]) * ALPHA_F);
    }

    // ---- stage F: GCN + temporal conv ----
    float acc[16];
    #pragma unroll
    for (int j = 0; j < 16; ++j) acc[j] = 0.f;

    for (int t = 0; t < 3; ++t) {
        // step1: G[v][12]: rows 0-4 = g1(f) = -sum_u C1[u][v] x[t][u][f]; rows 5-9 = g2(f)
        for (int i = tid; i < 310; i += 256) {
            int v = i / 5, f = i - v * 5;
            float g1 = 0.f, g2 = 0.f;
            const float* xa = lds + L_SX + t * 310 + f;
            for (int u = 0; u < 62; ++u) {
                float xv = xa[u * 5];
                g1 -= lds[L_A + u * 62 + v] * xv;
                g2 += lds[L_B + u * 62 + v] * xv;
            }
            lds[L_D + D_G + v * 12 + f]     = g1;
            lds[L_D + D_G + v * 12 + 5 + f] = g2;
        }
        __syncthreads();
        // step2: gcn[v][o] = relu(g0.th[0:5] + G[v][0:10].th[5:15]) -> C[v][64]
        #pragma unroll
        for (int j = 0; j < 16; ++j) {
            if (j < nv) {
                int v = q + 4 * j;
                float4 r0 = *(const float4*)&lds[L_D + D_G + v * 12];
                float4 r1 = *(const float4*)&lds[L_D + D_G + v * 12 + 4];
                float r2a = lds[L_D + D_G + v * 12 + 8];
                float r2b = lds[L_D + D_G + v * 12 + 9];
                float dv = lds[L_D + D_DIAG + v];
                float s = 0.f;
                #pragma unroll
                for (int f = 0; f < 5; ++f)
                    s += dv * lds[L_SX + t * 310 + v * 5 + f] * th[f];
                s += r0.x * th[5] + r0.y * th[6] + r0.z * th[7] + r0.w * th[8];
                s += r1.x * th[9] + r1.y * th[10] + r1.z * th[11] + r1.w * th[12];
                s += r2a * th[13] + r2b * th[14];
                lds[L_C + v * 64 + o] = fmaxf(s, 0.f);
            }
        }
        __syncthreads();
        // step3: acc[j] += sum_c gcn[v][c] * tw[o][c][t]   (b128 broadcast reads)
        const float* twtp = twt + t * 4096;
        for (int c4 = 0; c4 < 16; ++c4) {
            float w0 = twtp[(4 * c4 + 0) * 64 + o];
            float w1 = twtp[(4 * c4 + 1) * 64 + o];
            float w2 = twtp[(4 * c4 + 2) * 64 + o];
            float w3 = twtp[(4 * c4 + 3) * 64 + o];
            #pragma unroll
            for (int j = 0; j < 16; ++j) {
                if (j < nv) {
                    float4 g4 = *(const float4*)&lds[L_C + (q + 4 * j) * 64 + 4 * c4];
                    acc[j] += g4.x * w0 + g4.y * w1 + g4.z * w2 + g4.w * w3;
                }
            }
        }
        __syncthreads();
    }

    // ---- epilogue: residual + relu + LayerNorm over o ----
    #pragma unroll
    for (int j = 0; j < 16; ++j) {
        if (j < nv) {
            int v = q + 4 * j;
            float r = rb_o;
            #pragma unroll
            for (int f = 0; f < 5; ++f) r += lds[L_SX + v * 5 + f] * rw5[f];  // x[:,0]
            float z = r + (acc[j] + tb_o) * INV_SQRT15;
            z = fmaxf(z, 0.f);
            float s1 = z, s2 = z * z;
            #pragma unroll
            for (int m = 1; m < 64; m <<= 1) {
                s1 += __shfl_xor(s1, m, 64);
                s2 += __shfl_xor(s2, m, 64);
            }
            float mean = s1 * 0.015625f;
            float var  = s2 * 0.015625f - mean * mean;
            out[XR_OFF + (size_t)b * 3968 + v * 64 + o] =
                (z - mean) * rsqrtf(var + 1e-5f) * gam + bet;
        }
    }
}

extern "C" void kernel_launch(void* const* d_in, const int* in_sizes, int n_in,
                              void* d_out, int out_size, void* d_ws, size_t ws_size,
                              hipStream_t stream) {
    const float* x   = (const float*)d_in[0];
    const float* U1  = (const float*)d_in[1];
    const float* U2  = (const float*)d_in[2];
    const float* U3  = (const float*)d_in[3];
    const float* be  = (const float*)d_in[4];
    const float* Ve  = (const float*)d_in[5];
    const float* W1  = (const float*)d_in[6];
    const float* W2  = (const float*)d_in[7];
    const float* W3  = (const float*)d_in[8];
    const float* bs  = (const float*)d_in[9];
    const float* Vs  = (const float*)d_in[10];
    const float* a   = (const float*)d_in[11];
    const float* Th  = (const float*)d_in[12];
    const float* tw  = (const float*)d_in[13];
    const float* tb  = (const float*)d_in[14];
    const float* rw  = (const float*)d_in[15];
    const float* rb  = (const float*)d_in[16];
    const float* gm  = (const float*)d_in[17];
    const float* bt  = (const float*)d_in[18];
    float* out = (float*)d_out;
    float* twt = (float*)d_ws;  // 12288 floats

    prep_kernel<<<48, 256, 0, stream>>>(tw, twt, out);
    stgcn_kernel<<<2048, 256, 0, stream>>>(x, U1, U2, U3, be, Ve, W1, W2, W3,
                                           bs, Vs, a, Th, twt, tb, rw, rb, gm, bt, out);
}